// Round 15
// baseline (171.970 us; speedup 1.0000x reference)
//
#include <hip/hip_runtime.h>
#include <hip/hip_bf16.h>

#define C_DIM 100000
#define N_ROW 512
#define K_DIM 512
#define OUT_HALF 51200000  // N_ROW * C_DIM
#define NSTRIP 391         // ceil(100000 / 256)

#define SCALE_F 64.0f
#define ALPHA_F 0.1f
#define COS_M_F 0.87758256189037276f
#define SIN_M_F 0.47942553860420301f
#define THRESH_F (-0.87758256189037276f)
#define MM_F 0.23971276930210151f

// ws layout (bytes)
#define WS_ASW 0u
#define WS_TARGET 524288u
#define WS_CTM 526336u
#define WS_FTL 528384u
#define WS_TNEW 530432u

typedef __attribute__((ext_vector_type(8))) short short8;
typedef __attribute__((ext_vector_type(4))) float f32x4;
typedef __attribute__((ext_vector_type(4))) int i32x4;

static __device__ __forceinline__ unsigned short f2bf(float f) {
  union { float f; unsigned u; } x; x.f = f;
  unsigned r = x.u + 0x7fffu + ((x.u >> 16) & 1u);
  return (unsigned short)(r >> 16);
}

// hardware v_cvt_pk_bf16_f32 path (RNE, same rounding as f2bf)
static __device__ __forceinline__ int pack_bf2(float lo, float hi) {
  __hip_bfloat162 h = __float22bfloat162_rn(make_float2(lo, hi));
  int r;
  __builtin_memcpy(&r, &h, 4);
  return r;
}

// ---------------------------------------------------------------------------
// N1: normalize embedding rows, write bf16 A in MFMA-fragment-ready layout.
// ---------------------------------------------------------------------------
__global__ __launch_bounds__(64) void prep_emb(const float* __restrict__ emb,
                                               unsigned short* __restrict__ Asw) {
  const int m = blockIdx.x;
  const int t = threadIdx.x;
  const float* row = emb + (size_t)m * K_DIM;
  float ss = 0.f;
#pragma unroll
  for (int d = 0; d < 8; ++d) { float v = row[t + 64 * d]; ss += v * v; }
#pragma unroll
  for (int off = 32; off > 0; off >>= 1) ss += __shfl_xor(ss, off, 64);
  const float inv = rsqrtf(ss);
  const int s = t >> 2, g = t & 3;
  short8 pack;
#pragma unroll
  for (int j = 0; j < 8; ++j) {
    int k = 32 * s + 4 * g + (j & 3) + 16 * (j >> 2);
    pack[j] = (short)f2bf(row[k] * inv);
  }
  size_t idx = ((size_t)(s * 32 + (m >> 4)) * 64 + (m & 15) + 16 * g) * 8;
  *(short8*)(Asw + idx) = pack;
}

// ---------------------------------------------------------------------------
// N3: per-row target logit in f32
// ---------------------------------------------------------------------------
__global__ __launch_bounds__(64) void target_k(const float* __restrict__ emb,
                                               const float* __restrict__ Kmat,
                                               const int* __restrict__ labels,
                                               float* __restrict__ target) {
  const int i = blockIdx.x;
  const int t = threadIdx.x;
  const int lab = labels[i];
  const float* row = emb + (size_t)i * K_DIM;
  float dot = 0.f, ess = 0.f, kss = 0.f;
#pragma unroll
  for (int d0 = 0; d0 < 8; ++d0) {
    int d = t + 64 * d0;
    float e = row[d];
    float k = Kmat[(size_t)d * C_DIM + lab];
    dot += e * k; ess += e * e; kss += k * k;
  }
#pragma unroll
  for (int off = 32; off > 0; off >>= 1) {
    dot += __shfl_xor(dot, off, 64);
    ess += __shfl_xor(ess, off, 64);
    kss += __shfl_xor(kss, off, 64);
  }
  if (t == 0) {
    float tg = dot * rsqrtf(ess) * rsqrtf(kss);
    tg = fminf(1.f, fmaxf(-1.f, tg));
    target[i] = tg;
  }
}

// ---------------------------------------------------------------------------
// N4: t_new, per-row cos_theta_m and final_target_logit
// ---------------------------------------------------------------------------
__global__ __launch_bounds__(512) void rowdata_k(const float* __restrict__ target,
                                                 const float* __restrict__ t_in,
                                                 float* __restrict__ ctm,
                                                 float* __restrict__ ftl,
                                                 float* __restrict__ tnew) {
  __shared__ float red[512];
  const int i = threadIdx.x;
  const float tg = target[i];
  red[i] = tg;
  __syncthreads();
  for (int s = 256; s > 0; s >>= 1) {
    if (i < s) red[i] += red[i + s];
    __syncthreads();
  }
  const float t_new = red[0] * (1.0f / 512.0f) * ALPHA_F + (1.f - ALPHA_F) * t_in[0];
  const float st = sqrtf(fmaxf(0.f, 1.f - tg * tg));
  const float cm = tg * COS_M_F - st * SIN_M_F;
  ctm[i] = cm;
  ftl[i] = (tg > THRESH_F) ? cm : (tg - MM_F);
  if (i == 0) tnew[0] = t_new;
}

// ---------------------------------------------------------------------------
// R15 (= R14 with compile fix): FUSED gemm (R13 structure verbatim), ONE
// change vs R13: the f32->bf16 staging conversion uses __float22bfloat162_rn
// (hw v_cvt_pk_bf16_f32, 1 instr / 2 elements) instead of manual bit-math
// (~5 instr / element). VALUBusy 29% was the busiest pipe.
// ---------------------------------------------------------------------------
__global__ __launch_bounds__(256, 3) void gemm_fused(
    const float* __restrict__ Kmat,
    const unsigned short* __restrict__ Asw,
    const float* __restrict__ ctm_a,
    const float* __restrict__ ftl_a,
    const float* __restrict__ tnew_p,
    const int* __restrict__ labels,
    float* __restrict__ out) {
  __shared__ __align__(16) char lds[33280];
  __shared__ float invn_s[256];

  const int tid = threadIdx.x;
  const int wv = tid >> 6;   // wave 0..3
  const int lane = tid & 63;

  // xcd-chunked decode: a strip's 8 m-blocks are bid-stride-8 on ONE xcd
  const int bid = blockIdx.x;
  const int xcd = bid & 7;
  const int n = bid >> 3;            // 0..391
  const int strip = xcd * 49 + (n >> 3);
  const int mblock = n & 7;
  if (strip >= NSTRIP) return;       // 8 masked blocks (grid 3136)
  const int c0 = strip * 256;
  const int mb0 = mblock * 64;

  // staging role: q = lane (col quad), g = wv (fragment k-group)
  const int q = lane, g = wv;
  const int cg = c0 + q * 4;
  const bool cok = (cg < C_DIM);     // float4 fully in-bounds (C%4==0)
  const int cs_w = q >> 2;           // written subtile 0..15
  const int w0 = (q & 3) * 4;        // col-within-subtile base
  unsigned waddr[4];
#pragma unroll
  for (int cc = 0; cc < 4; ++cc)
    waddr[cc] = (unsigned)(cs_w * 1024 + ((g << 4) + ((w0 + cc) ^ cs_w)) * 16);

  f32x4 ssq = (f32x4){0.f, 0.f, 0.f, 0.f};
  f32x4 acc[4][4];
#pragma unroll
  for (int i = 0; i < 4; ++i)
#pragma unroll
    for (int j = 0; j < 4; ++j) acc[i][j] = (f32x4){0.f, 0.f, 0.f, 0.f};

  // ---- prologue: stage tile 0 into buf0 ----
  {
    f32x4 v[8];
    const float* rp = Kmat + (size_t)(4 * g) * C_DIM + cg;
#pragma unroll
    for (int i = 0; i < 4; ++i) {
      v[i] = (f32x4){0.f, 0.f, 0.f, 0.f};
      v[4 + i] = (f32x4){0.f, 0.f, 0.f, 0.f};
      if (cok) {
        v[i] = *(const f32x4*)(rp + (size_t)i * C_DIM);
        v[4 + i] = *(const f32x4*)(rp + (size_t)(16 + i) * C_DIM);
      }
    }
#pragma unroll
    for (int i = 0; i < 8; ++i) ssq += v[i] * v[i];
#pragma unroll
    for (int cc = 0; cc < 4; ++cc) {
      i32x4 pk;
#pragma unroll
      for (int k = 0; k < 4; ++k)
        pk[k] = pack_bf2(v[2 * k][cc], v[2 * k + 1][cc]);
      *(i32x4*)(lds + waddr[cc]) = pk;
    }
  }
  __syncthreads();

  // ---- main K-loop: 16 steps, double-buffered, one barrier/step ----
#pragma unroll 2
  for (int s = 0; s < 16; ++s) {
    // issue next tile's 8 loads FIRST (latency hides under Y/X/MFMA)
    f32x4 nv[8];
#pragma unroll
    for (int i = 0; i < 8; ++i) nv[i] = (f32x4){0.f, 0.f, 0.f, 0.f};
    if (s < 15 && cok) {
      const float* rp = Kmat + (size_t)((s + 1) * 32 + 4 * g) * C_DIM + cg;
#pragma unroll
      for (int i = 0; i < 4; ++i) {
        nv[i] = *(const f32x4*)(rp + (size_t)i * C_DIM);
        nv[4 + i] = *(const f32x4*)(rp + (size_t)(16 + i) * C_DIM);
      }
    }

    // Y fragments (emb side) from pre-swizzled global (L2-resident)
    short8 Y[4];
#pragma unroll
    for (int ms = 0; ms < 4; ++ms) {
      const int msub = mblock * 4 + ms;
      Y[ms] = *(const short8*)(Asw + (size_t)((s * 32 + msub) * 64 + lane) * 8);
    }

    // X fragments: contiguous short8 from fragment-major LDS (swizzled slot)
    short8 X[4];
    const char* rb = lds + (s & 1) * 16384;
#pragma unroll
    for (int i = 0; i < 4; ++i) {
      const int cs = wv * 4 + i;
      X[i] = *(const short8*)(rb + cs * 1024 +
                              ((lane & 48) + ((lane & 15) ^ cs)) * 16);
    }

#pragma unroll
    for (int i = 0; i < 4; ++i)
#pragma unroll
      for (int ms = 0; ms < 4; ++ms)
        acc[i][ms] =
            __builtin_amdgcn_mfma_f32_16x16x32_bf16(X[i], Y[ms], acc[i][ms], 0, 0, 0);

    // convert + stage tile s+1 into the other buffer (hw cvt_pk path)
    if (s < 15) {
#pragma unroll
      for (int i = 0; i < 8; ++i) ssq += nv[i] * nv[i];
      char* dst = lds + ((s + 1) & 1) * 16384;
#pragma unroll
      for (int cc = 0; cc < 4; ++cc) {
        i32x4 pk;
#pragma unroll
        for (int k = 0; k < 4; ++k)
          pk[k] = pack_bf2(nv[2 * k][cc], nv[2 * k + 1][cc]);
        *(i32x4*)(dst + waddr[cc]) = pk;
      }
    }
    __syncthreads();
  }

  // ---- per-block column norms (reuse buf0 area: loop is done) ----
  *(f32x4*)(lds + (g * 64 + q) * 16) = ssq;
  __syncthreads();
  if (tid < 64) {
    f32x4 ssum = *(const f32x4*)(lds + tid * 16);
#pragma unroll
    for (int gg = 1; gg < 4; ++gg)
      ssum += *(const f32x4*)(lds + (gg * 64 + tid) * 16);
    f32x4 iv;
#pragma unroll
    for (int j = 0; j < 4; ++j) iv[j] = rsqrtf(fmaxf(ssum[j], 1e-30f));
    *(f32x4*)&invn_s[tid * 4] = iv;
  }
  __syncthreads();

  // ---- epilogue: LDS-staged, row-contiguous 1 KB NT stores (verbatim R8) ----
#define EPV(r, c) (*(f32x4*)(lds + ((size_t)(r) * 260 + (c)) * 4))
  const float t_new = tnew_p[0];
  const int cq = (lane >> 4) * 4;

#pragma unroll
  for (int h = 0; h < 2; ++h) {  // row halves: rows mb0+32h .. +31
    float ctm2[2], ftl2[2];
    int lab2[2];
#pragma unroll
    for (int u = 0; u < 2; ++u) {
      const int m = mb0 + h * 32 + u * 16 + (lane & 15);
      ctm2[u] = ctm_a[m];
      ftl2[u] = ftl_a[m];
      lab2[u] = labels[m];
    }
#pragma unroll
    for (int o = 0; o < 2; ++o) {  // 0: ct, 1: origin_cos
      __syncthreads();             // guard LDS buffer reuse
#pragma unroll
      for (int u = 0; u < 2; ++u) {
        const int ms = h * 2 + u;
#pragma unroll
        for (int cs = 0; cs < 4; ++cs) {
          const int cl = wv * 64 + cs * 16 + cq;  // block-local col
          const int c = c0 + cl;
          const f32x4 a = acc[cs][ms];
          const f32x4 inv4 = *(const f32x4*)&invn_s[cl];
          f32x4 vv;
#pragma unroll
          for (int r = 0; r < 4; ++r) {
            float cosv = a[r] * inv4[r];
            cosv = fminf(1.f, fmaxf(-1.f, cosv));
            if (o) {
              vv[r] = cosv * SCALE_F;
            } else {
              float hard = cosv * (t_new + cosv);
              float v = (cosv > ctm2[u]) ? hard : cosv;
              if (c + r == lab2[u]) v = ftl2[u];
              vv[r] = v * SCALE_F;
            }
          }
          EPV(u * 16 + (lane & 15), cl) = vv;
        }
      }
      __syncthreads();
      // stream 32 rows x 1 KB: each wave-instruction = 1 KB CONTIGUOUS
      float* const obase = out + (o ? (size_t)OUT_HALF : (size_t)0);
      const int c = c0 + lane * 4;
      if (c < C_DIM) {  // 4-col granular (C%4==0)
#pragma unroll
        for (int i = 0; i < 8; ++i) {
          const int rl = wv * 8 + i;  // 0..31
          const int m = mb0 + h * 32 + rl;
          const f32x4 v = EPV(rl, lane * 4);
          __builtin_nontemporal_store(v, (f32x4*)(obase + (size_t)m * C_DIM + c));
        }
      }
    }
  }
#undef EPV
}

extern "C" void kernel_launch(void* const* d_in, const int* in_sizes, int n_in,
                              void* d_out, int out_size, void* d_ws, size_t ws_size,
                              hipStream_t stream) {
  const float* emb = (const float*)d_in[0];
  const float* Kmat = (const float*)d_in[1];
  const float* t_in = (const float*)d_in[2];
  const int* labels = (const int*)d_in[3];
  float* out = (float*)d_out;

  char* ws = (char*)d_ws;
  unsigned short* Asw = (unsigned short*)(ws + WS_ASW);
  float* target = (float*)(ws + WS_TARGET);
  float* ctm = (float*)(ws + WS_CTM);
  float* ftl = (float*)(ws + WS_FTL);
  float* tnew = (float*)(ws + WS_TNEW);

  prep_emb<<<512, 64, 0, stream>>>(emb, Asw);
  target_k<<<512, 64, 0, stream>>>(emb, Kmat, labels, target);
  rowdata_k<<<1, 512, 0, stream>>>(target, t_in, ctm, ftl, tnew);

  // 8 XCDs x 49 strip-slots x 8 m-blocks = 3136 (8 masked; 391 strips)
  gemm_fused<<<3136, 256, 0, stream>>>(Kmat, Asw, ctm, ftl, tnew, labels, out);
}